// Round 2
// baseline (444.982 us; speedup 1.0000x reference)
//
#include <hip/hip_runtime.h>

#define L 1024
#define BLOCK 256     // 4 waves per block
#define NITER 8       // rows per wave (persistent): grid = rows / (4*NITER)

__device__ __forceinline__ float soft_thr(float c, float thr) {
    float a = fabsf(c);
    return (a >= thr) ? copysignf(a - thr, c) : 0.0f;
}

__device__ __forceinline__ int imin2(int a, int b) { return (a < b) ? a : b; }
__device__ __forceinline__ int imax2(int a, int b) { return (a > b) ? a : b; }

// ---- exact median of the 512 |cd1| values held 8-per-lane across the wave.
// Direction-encoded integer bitonic sort (keys = bit patterns of non-negative
// floats, monotone as signed int; per-lane direction folded in via XOR masks),
// final k=512 phase truncated to the j=256 split + max/min reductions:
//   sorted[255] = max(lower 256), sorted[256] = min(upper 256).
__device__ __forceinline__ float median512(const float (&cd1)[8], int lane) {
    int w[8];
    const int b0 = -(int)( lane       & 1);
    const int b1 = -(int)((lane >> 1) & 1);
    const int b2 = -(int)((lane >> 2) & 1);
    const int b3 = -(int)((lane >> 3) & 1);
    const int b4 = -(int)((lane >> 4) & 1);
    const int b5 = -(int)((lane >> 5) & 1);

    #pragma unroll
    for (int r = 0; r < 8; ++r)
        w[r] = (__float_as_int(cd1[r]) & 0x7fffffff) ^ b0;

    #define CE(a, c) { int _lo = imin2(w[a], w[c]); int _hi = imax2(w[a], w[c]); \
                       w[a] = _lo; w[c] = _hi; }

    // in-lane Batcher odd-even mergesort of 8 (19 CEs), ascending in w-space
    CE(0,1) CE(2,3) CE(4,5) CE(6,7)
    CE(0,2) CE(1,3) CE(4,6) CE(5,7)
    CE(1,2) CE(5,6)
    CE(0,4) CE(1,5) CE(2,6) CE(3,7)
    CE(2,4) CE(3,5)
    CE(1,2) CE(3,4) CE(5,6)

    #define XORW(T) { const int _t = (T); \
        _Pragma("unroll") for (int r = 0; r < 8; ++r) w[r] ^= _t; }

    #define CROSS_STAGE(LM) { const bool _up = (lane & (LM)) != 0; \
        _Pragma("unroll") for (int r = 0; r < 8; ++r) { \
            int _o = __shfl_xor(w[r], (LM)); \
            w[r] = _up ? imax2(w[r], _o) : imin2(w[r], _o); } }

    #define INLANE3() { \
        CE(0,4) CE(1,5) CE(2,6) CE(3,7) \
        CE(0,2) CE(1,3) CE(4,6) CE(5,7) \
        CE(0,1) CE(2,3) CE(4,5) CE(6,7) }

    XORW(b0 ^ b1); CROSS_STAGE(1);                                                             INLANE3();  // k=16
    XORW(b1 ^ b2); CROSS_STAGE(2);  CROSS_STAGE(1);                                            INLANE3();  // k=32
    XORW(b2 ^ b3); CROSS_STAGE(4);  CROSS_STAGE(2); CROSS_STAGE(1);                            INLANE3();  // k=64
    XORW(b3 ^ b4); CROSS_STAGE(8);  CROSS_STAGE(4); CROSS_STAGE(2); CROSS_STAGE(1);            INLANE3();  // k=128
    XORW(b4 ^ b5); CROSS_STAGE(16); CROSS_STAGE(8); CROSS_STAGE(4); CROSS_STAGE(2); CROSS_STAGE(1); INLANE3();  // k=256
    XORW(b5);      CROSS_STAGE(32);   // k=512 bitonic split only (back in u-space)

    int zmx = imax2(imax2(imax2(w[0], w[1]), imax2(w[2], w[3])),
                    imax2(imax2(w[4], w[5]), imax2(w[6], w[7])));
    int zmn = imin2(imin2(imin2(w[0], w[1]), imin2(w[2], w[3])),
                    imin2(imin2(w[4], w[5]), imin2(w[6], w[7])));
    int z = (lane & 32) ? ~zmn : zmx;   // upper half reduces min via ~ trick
    #pragma unroll
    for (int m = 1; m <= 16; m <<= 1)
        z = imax2(z, __shfl_xor(z, m));
    const float m0 = __int_as_float(__shfl(z, 0));      // sorted[255]
    const float m1 = __int_as_float(~__shfl(z, 32));    // sorted[256]

    #undef CE
    #undef XORW
    #undef CROSS_STAGE
    #undef INLANE3

    return 0.5f * (m0 + m1);
}

// Process one row held in `in`; issue prefetch of the next row into `pref`
// right after `in` is consumed (so the sort hides the load latency).
template<bool PREF>
__device__ __forceinline__ void process_row(const float4 (&in)[4], float4 (&pref)[4],
        const float* __restrict__ pref_src, float* __restrict__ orow, int lane) {
    constexpr float IS2 = 0.70710678118654752f;
    constexpr float SQRT_2LOGL = 3.7232974111f;   // f32(sqrt(2*ln(1024)))

    // ---- level 1 DWT: lane owns ca1/cd1 pair indices {128j + 2*lane, +1}
    float ca1[8], cd1[8];
    #pragma unroll
    for (int j = 0; j < 4; ++j) {
        ca1[2*j]   = (in[j].x + in[j].y) * IS2;
        cd1[2*j]   = (in[j].x - in[j].y) * IS2;
        ca1[2*j+1] = (in[j].z + in[j].w) * IS2;
        cd1[2*j+1] = (in[j].z - in[j].w) * IS2;
    }

    // `in` is dead now — issue next row's loads; they stay in flight across the sort
    if (PREF) {
        #pragma unroll
        for (int j = 0; j < 4; ++j)
            pref[j] = ((const float4*)pref_src)[j * 64 + lane];
    }

    // ---- level 2: lane owns ca2/cd2 at index 64j + lane
    float ca2[4], cd2[4];
    #pragma unroll
    for (int j = 0; j < 4; ++j) {
        ca2[j] = (ca1[2*j] + ca1[2*j+1]) * IS2;
        cd2[j] = (ca1[2*j] - ca1[2*j+1]) * IS2;
    }

    // ---- level 3: adjacent-lane combine; even lane 2m holds ca3/cd3[32j + m]
    float ca3[4], cd3[4];
    #pragma unroll
    for (int j = 0; j < 4; ++j) {
        float o = __shfl_xor(ca2[j], 1);
        ca3[j] = (ca2[j] + o) * IS2;
        cd3[j] = (ca2[j] - o) * IS2;
    }

    const float median = median512(cd1, lane);
    const float lam  = (median / 0.6745f) * SQRT_2LOGL;
    const float thr1 = lam;                      // / log2(2)
    const float thr2 = lam / 1.5849625007f;      // / log2(3)
    const float thr3 = lam * 0.5f;               // / log2(4)

    // ---- reconstruction
    #pragma unroll
    for (int j = 0; j < 4; ++j) {
        float c3 = __shfl(ca3[j], lane & 62);
        float d3 = soft_thr(__shfl(cd3[j], lane & 62), thr3);
        float ca2r = ((lane & 1) == 0) ? (c3 + d3) * IS2 : (c3 - d3) * IS2;

        float d2 = soft_thr(cd2[j], thr2);
        float ca1r0 = (ca2r + d2) * IS2;
        float ca1r1 = (ca2r - d2) * IS2;

        float d10 = soft_thr(cd1[2*j],   thr1);
        float d11 = soft_thr(cd1[2*j+1], thr1);
        float4 o;
        o.x = (ca1r0 + d10) * IS2;
        o.y = (ca1r0 - d10) * IS2;
        o.z = (ca1r1 + d11) * IS2;
        o.w = (ca1r1 - d11) * IS2;
        ((float4*)orow)[j * 64 + lane] = o;
    }
}

__global__ __launch_bounds__(BLOCK, 4) void wavelet_denoise_kernel(
        const float* __restrict__ x, float* __restrict__ out) {
    const int lane = threadIdx.x & 63;
    const int wid  = threadIdx.x >> 6;
    const long long wave = (long long)blockIdx.x * 4 + wid;
    const long long row0 = wave * NITER;
    const float* xr = x + row0 * L;
    float* orow = out + row0 * L;

    float4 bufA[4], bufB[4];
    #pragma unroll
    for (int j = 0; j < 4; ++j)
        bufA[j] = ((const float4*)xr)[j * 64 + lane];

    #pragma unroll
    for (int it = 0; it < NITER; it += 2) {
        process_row<true>(bufA, bufB, xr + (long long)(it + 1) * L,
                          orow + (long long)it * L, lane);
        if (it + 2 < NITER) {
            process_row<true>(bufB, bufA, xr + (long long)(it + 2) * L,
                              orow + (long long)(it + 1) * L, lane);
        } else {
            process_row<false>(bufB, bufA, nullptr,
                               orow + (long long)(it + 1) * L, lane);
        }
    }
}

extern "C" void kernel_launch(void* const* d_in, const int* in_sizes, int n_in,
                              void* d_out, int out_size, void* d_ws, size_t ws_size,
                              hipStream_t stream) {
    const float* x = (const float*)d_in[0];
    float* out = (float*)d_out;
    const int rows = in_sizes[0] / L;           // 65536
    const int blocks = rows / (4 * NITER);      // 2048
    wavelet_denoise_kernel<<<blocks, BLOCK, 0, stream>>>(x, out);
}

// Round 3
// 435.941 us; speedup vs baseline: 1.0207x; 1.0207x over previous
//
#include <hip/hip_runtime.h>

#define L 1024
#define BLOCK 256   // 4 waves, 1 row per wave

__device__ __forceinline__ float soft_thr(float c, float thr) {
    float a = fabsf(c);
    return (a >= thr) ? copysignf(a - thr, c) : 0.0f;
}

__device__ __forceinline__ int imin2(int a, int b) { return (a < b) ? a : b; }
__device__ __forceinline__ int imax2(int a, int b) { return (a > b) ? a : b; }

// __launch_bounds__(256, 8): 8 waves/EU min -> allocator targets <=64 VGPR,
// which is the 8-wave/SIMD occupancy bracket (waves halve at 64/128/256).
// Live set across the sort is ~45 regs, so this should fit without spills.
__global__ __launch_bounds__(BLOCK, 8) void wavelet_denoise_kernel(
        const float* __restrict__ x, float* __restrict__ out) {
    constexpr float IS2 = 0.70710678118654752f;
    constexpr float SQRT_2LOGL = 3.7232974111f;   // f32(sqrt(2*ln(1024)))

    const int lane = threadIdx.x & 63;
    const int wid  = threadIdx.x >> 6;
    const long long row = (long long)blockIdx.x * 4 + wid;
    const float* xr = x + row * L;
    float* orow = out + row * L;

    // ---- load: 4 coalesced float4 chunks; chunk j = elements (j*64+lane)*4 .. +3
    float4 in[4];
    #pragma unroll
    for (int j = 0; j < 4; ++j)
        in[j] = ((const float4*)xr)[j * 64 + lane];

    // ---- level 1 DWT: lane owns ca1/cd1 pair indices {128j + 2*lane, +1}
    float cd1[8];
    float ca2[4], cd2[4];
    #pragma unroll
    for (int j = 0; j < 4; ++j) {
        float a0 = (in[j].x + in[j].y) * IS2;
        float a1 = (in[j].z + in[j].w) * IS2;
        cd1[2*j]   = (in[j].x - in[j].y) * IS2;
        cd1[2*j+1] = (in[j].z - in[j].w) * IS2;
        // ---- level 2 fused: lane owns ca2/cd2 at index 64j + lane
        ca2[j] = (a0 + a1) * IS2;
        cd2[j] = (a0 - a1) * IS2;
    }

    // ---- level 3: adjacent-lane combine; even lane 2m holds ca3/cd3[32j + m]
    float ca3[4], cd3[4];
    #pragma unroll
    for (int j = 0; j < 4; ++j) {
        float o = __shfl_xor(ca2[j], 1);
        ca3[j] = (ca2[j] + o) * IS2;   // valid on even lanes (odd lanes: unused garbage)
        cd3[j] = (ca2[j] - o) * IS2;
    }

    // ---- exact median of 512 |cd1| -------------------------------------------
    // Direction-encoded integer bitonic: keys = bit patterns of |cd1| (monotone
    // as signed int for non-negative floats); per-element sort direction for
    // k>=8 depends only on lane bits, folded into the key via XOR masks so every
    // compare-exchange is plain min/max. Final k=512 phase truncated to the
    // j=256 split: sorted[255] = max(lower 256), sorted[256] = min(upper 256).
    int w[8];
    const int b0 = -(int)( lane       & 1);
    const int b1 = -(int)((lane >> 1) & 1);
    const int b2 = -(int)((lane >> 2) & 1);
    const int b3 = -(int)((lane >> 3) & 1);
    const int b4 = -(int)((lane >> 4) & 1);
    const int b5 = -(int)((lane >> 5) & 1);

    #pragma unroll
    for (int r = 0; r < 8; ++r)
        w[r] = (__float_as_int(cd1[r]) & 0x7fffffff) ^ b0;

    #define CE(a, c) { int _lo = imin2(w[a], w[c]); int _hi = imax2(w[a], w[c]); \
                       w[a] = _lo; w[c] = _hi; }

    // in-lane Batcher odd-even mergesort of 8 (19 CEs), ascending in w-space
    CE(0,1) CE(2,3) CE(4,5) CE(6,7)
    CE(0,2) CE(1,3) CE(4,6) CE(5,7)
    CE(1,2) CE(5,6)
    CE(0,4) CE(1,5) CE(2,6) CE(3,7)
    CE(2,4) CE(3,5)
    CE(1,2) CE(3,4) CE(5,6)

    #define XORW(T) { const int _t = (T); \
        _Pragma("unroll") for (int r = 0; r < 8; ++r) w[r] ^= _t; }

    #define CROSS_STAGE(LM) { const bool _up = (lane & (LM)) != 0; \
        _Pragma("unroll") for (int r = 0; r < 8; ++r) { \
            int _o = __shfl_xor(w[r], (LM)); \
            w[r] = _up ? imax2(w[r], _o) : imin2(w[r], _o); } }

    #define INLANE3() { \
        CE(0,4) CE(1,5) CE(2,6) CE(3,7) \
        CE(0,2) CE(1,3) CE(4,6) CE(5,7) \
        CE(0,1) CE(2,3) CE(4,5) CE(6,7) }

    XORW(b0 ^ b1); CROSS_STAGE(1);                                                             INLANE3();  // k=16
    XORW(b1 ^ b2); CROSS_STAGE(2);  CROSS_STAGE(1);                                            INLANE3();  // k=32
    XORW(b2 ^ b3); CROSS_STAGE(4);  CROSS_STAGE(2); CROSS_STAGE(1);                            INLANE3();  // k=64
    XORW(b3 ^ b4); CROSS_STAGE(8);  CROSS_STAGE(4); CROSS_STAGE(2); CROSS_STAGE(1);            INLANE3();  // k=128
    XORW(b4 ^ b5); CROSS_STAGE(16); CROSS_STAGE(8); CROSS_STAGE(4); CROSS_STAGE(2); CROSS_STAGE(1); INLANE3();  // k=256
    XORW(b5);      CROSS_STAGE(32);   // k=512 bitonic split only (back in u-space)

    // ranks 255/256: max of lower 256 / min of upper 256
    int zmx = imax2(imax2(imax2(w[0], w[1]), imax2(w[2], w[3])),
                    imax2(imax2(w[4], w[5]), imax2(w[6], w[7])));
    int zmn = imin2(imin2(imin2(w[0], w[1]), imin2(w[2], w[3])),
                    imin2(imin2(w[4], w[5]), imin2(w[6], w[7])));
    int z = (lane & 32) ? ~zmn : zmx;   // upper half reduces min via ~ trick
    #pragma unroll
    for (int m = 1; m <= 16; m <<= 1)
        z = imax2(z, __shfl_xor(z, m));
    const float m0 = __int_as_float(__shfl(z, 0));      // sorted[255]
    const float m1 = __int_as_float(~__shfl(z, 32));    // sorted[256]

    #undef CE
    #undef XORW
    #undef CROSS_STAGE
    #undef INLANE3

    const float median = 0.5f * (m0 + m1);
    const float lam  = (median / 0.6745f) * SQRT_2LOGL;
    const float thr1 = lam;                      // / log2(2)
    const float thr2 = lam / 1.5849625007f;      // / log2(3)
    const float thr3 = lam * 0.5f;               // / log2(4)

    // ---- reconstruction (all local / single shuffle per level-3 fetch)
    #pragma unroll
    for (int j = 0; j < 4; ++j) {
        float c3 = __shfl(ca3[j], lane & 62);
        float d3 = soft_thr(__shfl(cd3[j], lane & 62), thr3);
        float ca2r = ((lane & 1) == 0) ? (c3 + d3) * IS2 : (c3 - d3) * IS2;

        float d2 = soft_thr(cd2[j], thr2);
        float ca1r0 = (ca2r + d2) * IS2;
        float ca1r1 = (ca2r - d2) * IS2;

        float d10 = soft_thr(cd1[2*j],   thr1);
        float d11 = soft_thr(cd1[2*j+1], thr1);
        float4 o;
        o.x = (ca1r0 + d10) * IS2;
        o.y = (ca1r0 - d10) * IS2;
        o.z = (ca1r1 + d11) * IS2;
        o.w = (ca1r1 - d11) * IS2;
        ((float4*)orow)[j * 64 + lane] = o;
    }
}

extern "C" void kernel_launch(void* const* d_in, const int* in_sizes, int n_in,
                              void* d_out, int out_size, void* d_ws, size_t ws_size,
                              hipStream_t stream) {
    const float* x = (const float*)d_in[0];
    float* out = (float*)d_out;
    const int rows = in_sizes[0] / L;           // 65536
    wavelet_denoise_kernel<<<rows / 4, BLOCK, 0, stream>>>(x, out);
}